// Round 1
// baseline (1172.639 us; speedup 1.0000x reference)
//
#include <hip/hip_runtime.h>

#define S_ 512
#define K_ 512
#define Q_ 64
#define D_ 256
#define H_ 8
#define SK_ (S_*K_)   // 262144
#define SQ_ (S_*Q_)   // 32768

typedef float f32x4 __attribute__((ext_vector_type(4)));
typedef short bf16x8 __attribute__((ext_vector_type(8)));
typedef short bf16x4 __attribute__((ext_vector_type(4)));

__device__ __forceinline__ short f2bf(float f) {
  unsigned u = __builtin_bit_cast(unsigned, f);
  u += 0x7fffu + ((u >> 16) & 1u);
  return (short)(u >> 16);
}
__device__ __forceinline__ float bf2f(short s) {
  unsigned u = ((unsigned)(unsigned short)s) << 16;
  return __builtin_bit_cast(float, u);
}

// ---------------- weight fp32 -> bf16 ----------------
__global__ void cvt_w_kernel(const float* Wq, const float* Wk, const float* Wv,
                             const float* Wl, short* out) {
  int i = blockIdx.x * 256 + threadIdx.x;           // 0 .. 4*65536
  const float* src = (i < 65536) ? Wq : (i < 131072) ? Wk : (i < 196608) ? Wv : Wl;
  out[i] = f2bf(src[i & 65535]);
}

// ---------------- gather key_t -> d_out (fp32) ----------------
__global__ void gather_kernel(const float* x, const int* tid, float* dout) {
  int g = blockIdx.x * 256 + threadIdx.x;
  int row = g >> 6, lane = g & 63;
  int src = tid[row];
  f32x4 v = *(const f32x4*)(x + (size_t)src * 256 + lane * 4);
  *(f32x4*)(dout + (size_t)row * 256 + lane * 4) = v;
}

// ---------------- gather query rows (fp32) ----------------
__global__ void gatherq_kernel(const float* x, const int* tid, const int* aid, float* qf) {
  int g = blockIdx.x * 256 + threadIdx.x;
  int row = g >> 6, lane = g & 63;        // row = s*64 + q
  int s = row >> 6;
  int k = aid[row];
  int src = tid[s * 512 + k];
  f32x4 v = *(const f32x4*)(x + (size_t)src * 256 + lane * 4);
  *(f32x4*)(qf + (size_t)row * 256 + lane * 4) = v;
}

// ---------------- GEMM: C[M x 256] = A @ W^T + bias ----------------
// wave: 64-col slice of W held in regs (b[4][8] = 128 VGPR), streams MT m-tiles.
// A-frag: A[m=lane&15][k=quad*8+j], B-frag: B[k][n] = W[n][k] (row n contig in k).
// C/D: col=lane&15, row=quad*4+reg  (m89-verified layouts).
template<int AF32, int VTRANS, int MT>
__global__ __launch_bounds__(256, 2) void gemm_kernel(const void* Ap, const short* Wb,
                                                      const float* bias, short* Cp, int M) {
  int wid  = blockIdx.x * 4 + (threadIdx.x >> 6);
  int lane = threadIdx.x & 63;
  int quad = lane >> 4, l16 = lane & 15;
  int cs = wid & 3;
  int chunk = wid >> 2;
  int colbase = cs << 6;

  bf16x8 b[4][8];
#pragma unroll
  for (int nt = 0; nt < 4; nt++)
#pragma unroll
    for (int kk = 0; kk < 8; kk++) {
      int n = colbase + nt * 16 + l16;
      b[nt][kk] = *(const bf16x8*)(Wb + n * 256 + kk * 32 + quad * 8);
    }
  float bv[4];
#pragma unroll
  for (int nt = 0; nt < 4; nt++) bv[nt] = bias[colbase + nt * 16 + l16];

  for (int mi = 0; mi < MT; mi++) {
    int rbase = (chunk * MT + mi) << 4;
    if (rbase >= M) return;
    bf16x8 a[8];
    if (AF32) {
      const float* Ar = (const float*)Ap + (size_t)(rbase + l16) * 256 + quad * 8;
#pragma unroll
      for (int kk = 0; kk < 8; kk++) {
        f32x4 f0 = *(const f32x4*)(Ar + kk * 32);
        f32x4 f1 = *(const f32x4*)(Ar + kk * 32 + 4);
        bf16x8 av;
#pragma unroll
        for (int j = 0; j < 4; j++) { av[j] = f2bf(f0[j]); av[j + 4] = f2bf(f1[j]); }
        a[kk] = av;
      }
    } else {
      const short* Ar = (const short*)Ap + (size_t)(rbase + l16) * 256 + quad * 8;
#pragma unroll
      for (int kk = 0; kk < 8; kk++) a[kk] = *(const bf16x8*)(Ar + kk * 32);
    }
    f32x4 acc[4];
#pragma unroll
    for (int nt = 0; nt < 4; nt++) acc[nt] = (f32x4){bv[nt], bv[nt], bv[nt], bv[nt]};
#pragma unroll
    for (int kk = 0; kk < 8; kk++)
#pragma unroll
      for (int nt = 0; nt < 4; nt++)
        acc[nt] = __builtin_amdgcn_mfma_f32_16x16x32_bf16(a[kk], b[nt][kk], acc[nt], 0, 0, 0);

    if (!VTRANS) {
#pragma unroll
      for (int nt = 0; nt < 4; nt++) {
        int col = colbase + nt * 16 + l16;
#pragma unroll
        for (int r = 0; r < 4; r++) {
          int row = rbase + quad * 4 + r;
          Cp[(size_t)row * 256 + col] = f2bf(acc[nt][r]);
        }
      }
    } else {
      // Vt[s][h][dh][key], key = row within s-chunk; 4 consecutive keys per lane -> 8B store
      int s = rbase >> 9;
      int keyb = (rbase & 511) + quad * 4;
#pragma unroll
      for (int nt = 0; nt < 4; nt++) {
        int col = colbase + nt * 16 + l16;
        int h = col >> 5, dh = col & 31;
        bf16x4 pk;
#pragma unroll
        for (int r = 0; r < 4; r++) pk[r] = f2bf(acc[nt][r]);
        *(bf16x4*)(Cp + ((((size_t)s * 8 + h) * 32 + dh) << 9) + keyb) = pk;
      }
    }
  }
}

// ---------------- attention per (s,h): 4 waves = 4 q-tiles of 16 ----------------
__global__ __launch_bounds__(256, 2) void attn_kernel(const short* Qp, const short* Kp,
                                                      const short* Vt, float* aout) {
  __shared__ short P[4][16][264];   // per-wave 16 x (256+8 pad) bf16, key-half buffer
  int bid = blockIdx.x;
  int s = bid >> 3, h = bid & 7;
  int w = threadIdx.x >> 6;          // wave = q-tile (mt)
  int lane = threadIdx.x & 63;
  int quad = lane >> 4, l16 = lane & 15;

  // Q fragment: A[m=q16][k=d]
  bf16x8 aq = *(const bf16x8*)(Qp + ((size_t)(s * 64 + w * 16 + l16)) * 256 + h * 32 + quad * 8);

  // scores: 32 n-tiles of keys, K-dim = DH = 32 = one MFMA step
  f32x4 sc[32];
  const short* kbase = Kp + (size_t)s * 512 * 256 + h * 32 + quad * 8;
  f32x4 zero = (f32x4){0.f, 0.f, 0.f, 0.f};
#pragma unroll
  for (int nt = 0; nt < 32; nt++) {
    int key = nt * 16 + l16;
    bf16x8 bk = *(const bf16x8*)(kbase + (size_t)key * 256);
    sc[nt] = __builtin_amdgcn_mfma_f32_16x16x32_bf16(aq, bk, zero, 0, 0, 0);
  }

  // row softmax (rows quad*4+r live in this lane; reduce across 16 lanes of the quad)
  float rmax[4], lsum[4];
#pragma unroll
  for (int r = 0; r < 4; r++) {
    float m = sc[0][r];
#pragma unroll
    for (int nt = 1; nt < 32; nt++) m = fmaxf(m, sc[nt][r]);
#pragma unroll
    for (int off = 1; off < 16; off <<= 1) m = fmaxf(m, __shfl_xor(m, off, 64));
    rmax[r] = m;
    float l = 0.f;
#pragma unroll
    for (int nt = 0; nt < 32; nt++) {
      float p = __expf((sc[nt][r] - m) * 0.0625f);   // 1/sqrt(D) = 1/16
      sc[nt][r] = p;
      l += p;
    }
#pragma unroll
    for (int off = 1; off < 16; off <<= 1) l += __shfl_xor(l, off, 64);
    lsum[r] = l;
  }

  // PV in two key-halves via LDS round-trip (C-layout -> A-layout)
  f32x4 o[2] = {zero, zero};
  const short* vbase = Vt + (((size_t)s * 8 + h) << 14);   // *32*512
  for (int half = 0; half < 2; half++) {
#pragma unroll
    for (int nt = 0; nt < 16; nt++) {
      int ntg = half * 16 + nt;
#pragma unroll
      for (int r = 0; r < 4; r++)
        P[w][quad * 4 + r][nt * 16 + l16] = f2bf(sc[ntg][r]);
    }
    __syncthreads();
#pragma unroll
    for (int kk = 0; kk < 8; kk++) {
      bf16x8 ap = *(const bf16x8*)&P[w][l16][kk * 32 + quad * 8];
#pragma unroll
      for (int nt2 = 0; nt2 < 2; nt2++) {
        const short* vb = vbase + ((size_t)(nt2 * 16 + l16) << 9) + half * 256 + kk * 32 + quad * 8;
        o[nt2] = __builtin_amdgcn_mfma_f32_16x16x32_bf16(ap, *(const bf16x8*)vb, o[nt2], 0, 0, 0);
      }
    }
    __syncthreads();
  }

  // epilogue: out = Qp + PV / l
#pragma unroll
  for (int nt2 = 0; nt2 < 2; nt2++)
#pragma unroll
    for (int r = 0; r < 4; r++) {
      int q = w * 16 + quad * 4 + r;
      int dh = nt2 * 16 + l16;
      size_t oq = ((size_t)(s * 64 + q)) * 256 + h * 32 + dh;
      aout[oq] = bf2f(Qp[oq]) + o[nt2][r] / lsum[r];
    }
}

// ---------------- LN1: fp32 in -> bf16 out ----------------
__global__ void ln1_kernel(const float* ain, const float* g1, const float* b1, short* out) {
  int g = blockIdx.x * 256 + threadIdx.x;
  int row = g >> 6, lane = g & 63;
  f32x4 v = *(const f32x4*)(ain + (size_t)row * 256 + lane * 4);
  float s = v[0] + v[1] + v[2] + v[3];
  float s2 = v[0]*v[0] + v[1]*v[1] + v[2]*v[2] + v[3]*v[3];
#pragma unroll
  for (int off = 1; off < 64; off <<= 1) { s += __shfl_xor(s, off, 64); s2 += __shfl_xor(s2, off, 64); }
  float mu = s * (1.f / 256.f);
  float var = s2 * (1.f / 256.f) - mu * mu;
  float inv = rsqrtf(var + 1e-5f);
  f32x4 gv = *(const f32x4*)(g1 + lane * 4);
  f32x4 bv = *(const f32x4*)(b1 + lane * 4);
  bf16x4 ov;
#pragma unroll
  for (int j = 0; j < 4; j++) ov[j] = f2bf((v[j] - mu) * inv * gv[j] + bv[j]);
  *(bf16x4*)(out + (size_t)row * 256 + lane * 4) = ov;
}

// ---------------- LN2 + scatter-add into d_out ----------------
__global__ void ln2_kernel(const short* ln1, const short* tmp, const float* g2, const float* b2,
                           const int* aid, float* dout) {
  int g = blockIdx.x * 256 + threadIdx.x;
  int row = g >> 6, lane = g & 63;      // row = s*64 + q
  bf16x4 a = *(const bf16x4*)(ln1 + (size_t)row * 256 + lane * 4);
  bf16x4 t = *(const bf16x4*)(tmp + (size_t)row * 256 + lane * 4);
  float v[4];
#pragma unroll
  for (int j = 0; j < 4; j++) v[j] = bf2f(a[j]) + fmaxf(bf2f(t[j]), 0.f);
  float s = v[0] + v[1] + v[2] + v[3];
  float s2 = v[0]*v[0] + v[1]*v[1] + v[2]*v[2] + v[3]*v[3];
#pragma unroll
  for (int off = 1; off < 64; off <<= 1) { s += __shfl_xor(s, off, 64); s2 += __shfl_xor(s2, off, 64); }
  float mu = s * (1.f / 256.f);
  float var = s2 * (1.f / 256.f) - mu * mu;
  float inv = rsqrtf(var + 1e-5f);
  f32x4 gv = *(const f32x4*)(g2 + lane * 4);
  f32x4 bv = *(const f32x4*)(b2 + lane * 4);
  int sIdx = row >> 6;
  int tgt = aid[row];
  float* op = dout + ((size_t)(sIdx * 512 + tgt)) * 256 + lane * 4;
  f32x4 cur = *(f32x4*)op;
#pragma unroll
  for (int j = 0; j < 4; j++) cur[j] += (v[j] - mu) * inv * gv[j] + bv[j];
  *(f32x4*)op = cur;
}

extern "C" void kernel_launch(void* const* d_in, const int* in_sizes, int n_in,
                              void* d_out, int out_size, void* d_ws, size_t ws_size,
                              hipStream_t stream) {
  const float* x   = (const float*)d_in[0];
  const int* tid   = (const int*)d_in[1];
  const int* aid   = (const int*)d_in[2];
  const float* Wq  = (const float*)d_in[3];
  const float* bq  = (const float*)d_in[4];
  const float* Wk  = (const float*)d_in[5];
  const float* bk  = (const float*)d_in[6];
  const float* Wv  = (const float*)d_in[7];
  const float* bv  = (const float*)d_in[8];
  const float* g1  = (const float*)d_in[9];
  const float* b1  = (const float*)d_in[10];
  const float* Wl  = (const float*)d_in[11];
  const float* bl  = (const float*)d_in[12];
  const float* g2  = (const float*)d_in[13];
  const float* b2  = (const float*)d_in[14];
  float* out = (float*)d_out;

  char* base = (char*)d_ws;
  short* Wqb = (short*)base;                       // 4 x 65536 bf16
  short* Wkb = Wqb + 65536;
  short* Wvb = Wkb + 65536;
  short* Wlb = Wvb + 65536;
  size_t off = 4ull * 65536 * 2;
  float* qf   = (float*)(base + off); off += (size_t)SQ_ * 256 * 4;   // query fp32
  short* Qpb  = (short*)(base + off); off += (size_t)SQ_ * 256 * 2;   // Qp bf16
  short* Kpb  = (short*)(base + off); off += (size_t)SK_ * 256 * 2;   // Kp bf16
  short* Vtb  = (short*)(base + off); off += (size_t)SK_ * 256 * 2;   // V^T bf16 [s,h,dh,key]
  float* attn = (float*)(base + off); off += (size_t)SQ_ * 256 * 4;   // attn out fp32
  short* ln1b = (short*)(base + off); off += (size_t)SQ_ * 256 * 2;   // LN1 bf16
  short* tmpb = (short*)(base + off); off += (size_t)SQ_ * 256 * 2;   // FFN pre-relu bf16
  (void)ws_size; (void)in_sizes; (void)n_in; (void)out_size;

  cvt_w_kernel<<<1024, 256, 0, stream>>>(Wq, Wk, Wv, Wl, Wqb);
  gather_kernel<<<SK_ / 4, 256, 0, stream>>>(x, tid, out);
  gatherq_kernel<<<SQ_ / 4, 256, 0, stream>>>(x, tid, aid, qf);
  gemm_kernel<1, 0, 8><<<SK_ / 128, 256, 0, stream>>>(out, Wkb, bk, Kpb, SK_);
  gemm_kernel<1, 1, 8><<<SK_ / 128, 256, 0, stream>>>(out, Wvb, bv, Vtb, SK_);
  gemm_kernel<1, 0, 8><<<SQ_ / 128, 256, 0, stream>>>(qf, Wqb, bq, Qpb, SQ_);
  attn_kernel<<<S_ * H_, 256, 0, stream>>>(Qpb, Kpb, Vtb, attn);
  ln1_kernel<<<SQ_ / 4, 256, 0, stream>>>(attn, g1, b1, ln1b);
  gemm_kernel<0, 0, 8><<<SQ_ / 128, 256, 0, stream>>>(ln1b, Wlb, bl, tmpb, SQ_);
  ln2_kernel<<<SQ_ / 4, 256, 0, stream>>>(ln1b, tmpb, g2, b2, aid, out);
}

// Round 2
// 940.178 us; speedup vs baseline: 1.2473x; 1.2473x over previous
//
#include <hip/hip_runtime.h>

#define S_ 512
#define K_ 512
#define Q_ 64
#define D_ 256
#define H_ 8
#define SK_ (S_*K_)   // 262144
#define SQ_ (S_*Q_)   // 32768

typedef float f32x4 __attribute__((ext_vector_type(4)));
typedef short bf16x8 __attribute__((ext_vector_type(8)));
typedef short bf16x4 __attribute__((ext_vector_type(4)));

__device__ __forceinline__ short f2bf(float f) {
  unsigned u = __builtin_bit_cast(unsigned, f);
  u += 0x7fffu + ((u >> 16) & 1u);
  return (short)(u >> 16);
}
__device__ __forceinline__ float bf2f(short s) {
  unsigned u = ((unsigned)(unsigned short)s) << 16;
  return __builtin_bit_cast(float, u);
}

__device__ __forceinline__ void async_copy16(short* lds, const short* g) {
  __builtin_amdgcn_global_load_lds(
      (const __attribute__((address_space(1))) void*)g,
      (__attribute__((address_space(3))) void*)lds, 16, 0, 0);
}

// ---------------- weight fp32 -> bf16 ----------------
__global__ void cvt_w_kernel(const float* Wq, const float* Wk, const float* Wv,
                             const float* Wl, short* out) {
  int i = blockIdx.x * 256 + threadIdx.x;
  const float* src = (i < 65536) ? Wq : (i < 131072) ? Wk : (i < 196608) ? Wv : Wl;
  out[i] = f2bf(src[i & 65535]);
}

// ---------------- gather key_t -> kb (bf16) ----------------
__global__ void gather_kernel(const float* x, const int* tid, short* kb) {
  int g = blockIdx.x * 256 + threadIdx.x;   // one thread per 8 elements
  int row = g >> 5, e = (g & 31) * 8;
  int src = tid[row];
  f32x4 v0 = *(const f32x4*)(x + (size_t)src * 256 + e);
  f32x4 v1 = *(const f32x4*)(x + (size_t)src * 256 + e + 4);
  bf16x8 o;
#pragma unroll
  for (int j = 0; j < 4; j++) { o[j] = f2bf(v0[j]); o[j + 4] = f2bf(v1[j]); }
  *(bf16x8*)(kb + (size_t)row * 256 + e) = o;
}

// ---------------- expand kb (bf16) -> d_out (fp32) ----------------
__global__ void expand_kernel(const short* kb, float* dout) {
  int g = blockIdx.x * 256 + threadIdx.x;   // per 8 elements
  bf16x8 v = *(const bf16x8*)(kb + (size_t)g * 8);
  f32x4 a, b;
#pragma unroll
  for (int j = 0; j < 4; j++) { a[j] = bf2f(v[j]); b[j] = bf2f(v[j + 4]); }
  *(f32x4*)(dout + (size_t)g * 8) = a;
  *(f32x4*)(dout + (size_t)g * 8 + 4) = b;
}

// ---------------- GEMM: C[M x 256] = A @ W^T + bias (A bf16, LDS-staged) ----
// Block: 128 rows x 256 cols. Wave w holds 64-col W-slice in regs (128 VGPR).
// A tile staged via global_load_lds (16B, XOR-swizzled chunks for balanced
// ds_read_b128 banks). 256 MFMA per wave per barrier.
// INDEXED: A row m maps to A[(m>>6)*512 + aid[m]] (query gather fused).
// VTRANS: write C transposed as Vt[s][h][dh][key].
template<int INDEXED, int VTRANS>
__global__ __launch_bounds__(256, 2) void gemm2_kernel(const short* A, const int* aid,
                                                       const short* Wb, const float* bias,
                                                       short* Cp) {
  __shared__ short As[128 * 256];   // 64 KB
  int w = threadIdx.x >> 6, lane = threadIdx.x & 63;
  int quad = lane >> 4, l16 = lane & 15;
  int rbase0 = blockIdx.x * 128;
  int colbase = w * 64;

  // B fragments: B[k][n] = W[n][k]; lane l16 -> col n, quad -> k-chunk
  bf16x8 b[4][8];
#pragma unroll
  for (int nt = 0; nt < 4; nt++)
#pragma unroll
    for (int kk = 0; kk < 8; kk++)
      b[nt][kk] = *(const bf16x8*)(Wb + (colbase + nt * 16 + l16) * 256 + kk * 32 + quad * 8);
  float bv[4];
#pragma unroll
  for (int nt = 0; nt < 4; nt++) bv[nt] = bias[colbase + nt * 16 + l16];

  // stage A tile: wave w covers rows w*32 .. w*32+31 (2 rows per inst)
  int cc = lane & 31;
#pragma unroll
  for (int i = 0; i < 16; i++) {
    int chunkLinear = w * 1024 + i * 64 + lane;
    int row = chunkLinear >> 5;
    int c = cc ^ (row & 15);                 // XOR swizzle (involutive)
    int m = rbase0 + row;
    int arow = INDEXED ? (((m >> 6) << 9) + aid[m]) : m;
    async_copy16(As + (size_t)(w * 1024 + i * 64) * 8,
                 A + (size_t)arow * 256 + c * 8);
  }
  __syncthreads();

  for (int mt = 0; mt < 8; mt++) {
    bf16x8 a[8];
#pragma unroll
    for (int kk = 0; kk < 8; kk++)
      a[kk] = *(const bf16x8*)(As + (mt * 16 + l16) * 256 + (((kk * 4 + quad) ^ l16) * 8));
    f32x4 acc[4];
#pragma unroll
    for (int nt = 0; nt < 4; nt++) acc[nt] = (f32x4){bv[nt], bv[nt], bv[nt], bv[nt]};
#pragma unroll
    for (int kk = 0; kk < 8; kk++)
#pragma unroll
      for (int nt = 0; nt < 4; nt++)
        acc[nt] = __builtin_amdgcn_mfma_f32_16x16x32_bf16(a[kk], b[nt][kk], acc[nt], 0, 0, 0);

    int rbase = rbase0 + mt * 16;
    if (!VTRANS) {
#pragma unroll
      for (int nt = 0; nt < 4; nt++) {
        int col = colbase + nt * 16 + l16;
#pragma unroll
        for (int r = 0; r < 4; r++)
          Cp[(size_t)(rbase + quad * 4 + r) * 256 + col] = f2bf(acc[nt][r]);
      }
    } else {
      int s = rbase >> 9;
      int keyb = (rbase & 511) + quad * 4;
#pragma unroll
      for (int nt = 0; nt < 4; nt++) {
        int col = colbase + nt * 16 + l16;
        int h = col >> 5, dh = col & 31;
        bf16x4 pk;
#pragma unroll
        for (int r = 0; r < 4; r++) pk[r] = f2bf(acc[nt][r]);
        *(bf16x4*)(Cp + ((((size_t)s * 8 + h) * 32 + dh) << 9) + keyb) = pk;
      }
    }
  }
}

// ---------------- attention per (s,h): 4 waves = 4 q-tiles of 16 ----------------
__global__ __launch_bounds__(256, 2) void attn_kernel(const short* Qp, const short* Kp,
                                                      const short* Vt, float* aout) {
  __shared__ short P[4][16][264];
  int bid = blockIdx.x;
  int s = bid >> 3, h = bid & 7;
  int w = threadIdx.x >> 6;
  int lane = threadIdx.x & 63;
  int quad = lane >> 4, l16 = lane & 15;

  bf16x8 aq = *(const bf16x8*)(Qp + ((size_t)(s * 64 + w * 16 + l16)) * 256 + h * 32 + quad * 8);

  f32x4 sc[32];
  const short* kbase = Kp + (size_t)s * 512 * 256 + h * 32 + quad * 8;
  f32x4 zero = (f32x4){0.f, 0.f, 0.f, 0.f};
#pragma unroll
  for (int nt = 0; nt < 32; nt++) {
    int key = nt * 16 + l16;
    bf16x8 bk = *(const bf16x8*)(kbase + (size_t)key * 256);
    sc[nt] = __builtin_amdgcn_mfma_f32_16x16x32_bf16(aq, bk, zero, 0, 0, 0);
  }

  float lsum[4];
#pragma unroll
  for (int r = 0; r < 4; r++) {
    float m = sc[0][r];
#pragma unroll
    for (int nt = 1; nt < 32; nt++) m = fmaxf(m, sc[nt][r]);
#pragma unroll
    for (int off = 1; off < 16; off <<= 1) m = fmaxf(m, __shfl_xor(m, off, 64));
    float l = 0.f;
#pragma unroll
    for (int nt = 0; nt < 32; nt++) {
      float p = __expf((sc[nt][r] - m) * 0.0625f);
      sc[nt][r] = p;
      l += p;
    }
#pragma unroll
    for (int off = 1; off < 16; off <<= 1) l += __shfl_xor(l, off, 64);
    lsum[r] = l;
  }

  f32x4 o[2] = {zero, zero};
  const short* vbase = Vt + (((size_t)s * 8 + h) << 14);
  for (int half = 0; half < 2; half++) {
#pragma unroll
    for (int nt = 0; nt < 16; nt++) {
      int ntg = half * 16 + nt;
#pragma unroll
      for (int r = 0; r < 4; r++)
        P[w][quad * 4 + r][nt * 16 + l16] = f2bf(sc[ntg][r]);
    }
    __syncthreads();
#pragma unroll
    for (int kk = 0; kk < 8; kk++) {
      bf16x8 ap = *(const bf16x8*)&P[w][l16][kk * 32 + quad * 8];
#pragma unroll
      for (int nt2 = 0; nt2 < 2; nt2++) {
        const short* vb = vbase + ((size_t)(nt2 * 16 + l16) << 9) + half * 256 + kk * 32 + quad * 8;
        o[nt2] = __builtin_amdgcn_mfma_f32_16x16x32_bf16(ap, *(const bf16x8*)vb, o[nt2], 0, 0, 0);
      }
    }
    __syncthreads();
  }

#pragma unroll
  for (int nt2 = 0; nt2 < 2; nt2++)
#pragma unroll
    for (int r = 0; r < 4; r++) {
      int q = w * 16 + quad * 4 + r;
      int dh = nt2 * 16 + l16;
      size_t oq = ((size_t)(s * 64 + q)) * 256 + h * 32 + dh;
      aout[oq] = bf2f(Qp[oq]) + o[nt2][r] / lsum[r];
    }
}

// ---------------- LN1: fp32 in -> bf16 out ----------------
__global__ void ln1_kernel(const float* ain, const float* g1, const float* b1, short* out) {
  int g = blockIdx.x * 256 + threadIdx.x;
  int row = g >> 6, lane = g & 63;
  f32x4 v = *(const f32x4*)(ain + (size_t)row * 256 + lane * 4);
  float s = v[0] + v[1] + v[2] + v[3];
  float s2 = v[0]*v[0] + v[1]*v[1] + v[2]*v[2] + v[3]*v[3];
#pragma unroll
  for (int off = 1; off < 64; off <<= 1) { s += __shfl_xor(s, off, 64); s2 += __shfl_xor(s2, off, 64); }
  float mu = s * (1.f / 256.f);
  float var = s2 * (1.f / 256.f) - mu * mu;
  float inv = rsqrtf(var + 1e-5f);
  f32x4 gv = *(const f32x4*)(g1 + lane * 4);
  f32x4 bv = *(const f32x4*)(b1 + lane * 4);
  bf16x4 ov;
#pragma unroll
  for (int j = 0; j < 4; j++) ov[j] = f2bf((v[j] - mu) * inv * gv[j] + bv[j]);
  *(bf16x4*)(out + (size_t)row * 256 + lane * 4) = ov;
}

// ---------------- LN2 + scatter-add into d_out ----------------
__global__ void ln2_kernel(const short* ln1, const short* tmp, const float* g2, const float* b2,
                           const int* aid, float* dout) {
  int g = blockIdx.x * 256 + threadIdx.x;
  int row = g >> 6, lane = g & 63;
  bf16x4 a = *(const bf16x4*)(ln1 + (size_t)row * 256 + lane * 4);
  bf16x4 t = *(const bf16x4*)(tmp + (size_t)row * 256 + lane * 4);
  float v[4];
#pragma unroll
  for (int j = 0; j < 4; j++) v[j] = bf2f(a[j]) + fmaxf(bf2f(t[j]), 0.f);
  float s = v[0] + v[1] + v[2] + v[3];
  float s2 = v[0]*v[0] + v[1]*v[1] + v[2]*v[2] + v[3]*v[3];
#pragma unroll
  for (int off = 1; off < 64; off <<= 1) { s += __shfl_xor(s, off, 64); s2 += __shfl_xor(s2, off, 64); }
  float mu = s * (1.f / 256.f);
  float var = s2 * (1.f / 256.f) - mu * mu;
  float inv = rsqrtf(var + 1e-5f);
  f32x4 gv = *(const f32x4*)(g2 + lane * 4);
  f32x4 bv = *(const f32x4*)(b2 + lane * 4);
  int sIdx = row >> 6;
  int tgt = aid[row];
  float* op = dout + ((size_t)(sIdx * 512 + tgt)) * 256 + lane * 4;
  f32x4 cur = *(f32x4*)op;
#pragma unroll
  for (int j = 0; j < 4; j++) cur[j] += (v[j] - mu) * inv * gv[j] + bv[j];
  *(f32x4*)op = cur;
}

extern "C" void kernel_launch(void* const* d_in, const int* in_sizes, int n_in,
                              void* d_out, int out_size, void* d_ws, size_t ws_size,
                              hipStream_t stream) {
  const float* x   = (const float*)d_in[0];
  const int* tid   = (const int*)d_in[1];
  const int* aid   = (const int*)d_in[2];
  const float* Wq  = (const float*)d_in[3];
  const float* bq  = (const float*)d_in[4];
  const float* Wk  = (const float*)d_in[5];
  const float* bk  = (const float*)d_in[6];
  const float* Wv  = (const float*)d_in[7];
  const float* bv  = (const float*)d_in[8];
  const float* g1  = (const float*)d_in[9];
  const float* b1  = (const float*)d_in[10];
  const float* Wl  = (const float*)d_in[11];
  const float* bl  = (const float*)d_in[12];
  const float* g2  = (const float*)d_in[13];
  const float* b2  = (const float*)d_in[14];
  float* out = (float*)d_out;

  // ws layout (~286 MB): Wb | kb | Qpb | Kpb. d_out doubles as scratch:
  // first half = Vt (bf16), second half = attn out (fp32), until expand.
  char* base = (char*)d_ws;
  short* Wqb = (short*)base;
  short* Wkb = Wqb + 65536;
  short* Wvb = Wkb + 65536;
  short* Wlb = Wvb + 65536;
  size_t off = 4ull * 65536 * 2;
  short* kb   = (short*)(base + off); off += (size_t)SK_ * 256 * 2;
  short* Qpb  = (short*)(base + off); off += (size_t)SQ_ * 256 * 2;
  short* Kpb  = (short*)(base + off); off += (size_t)SK_ * 256 * 2;
  short* ln1b = Qpb;                       // Qp dead after attn
  short* tmpb = Kpb;                       // Kp dead after attn
  short* Vtb  = (short*)d_out;             // first 134 MB of d_out
  float* aout = (float*)((char*)d_out + (size_t)SK_ * 256 * 2);
  (void)ws_size; (void)in_sizes; (void)n_in; (void)out_size;

  cvt_w_kernel<<<1024, 256, 0, stream>>>(Wq, Wk, Wv, Wl, Wqb);
  gather_kernel<<<SK_ / 8, 256, 0, stream>>>(x, tid, kb);
  gemm2_kernel<0, 0><<<SK_ / 128, 256, 0, stream>>>(kb, nullptr, Wkb, bk, Kpb);
  gemm2_kernel<0, 1><<<SK_ / 128, 256, 0, stream>>>(kb, nullptr, Wvb, bv, Vtb);
  gemm2_kernel<1, 0><<<SQ_ / 128, 256, 0, stream>>>(kb, aid, Wqb, bq, Qpb);
  attn_kernel<<<S_ * H_, 256, 0, stream>>>(Qpb, Kpb, Vtb, aout);
  ln1_kernel<<<SQ_ / 4, 256, 0, stream>>>(aout, g1, b1, ln1b);
  gemm2_kernel<0, 0><<<SQ_ / 128, 256, 0, stream>>>(ln1b, nullptr, Wlb, bl, tmpb);
  expand_kernel<<<SK_ / 8, 256, 0, stream>>>(kb, out);
  ln2_kernel<<<SQ_ / 4, 256, 0, stream>>>(ln1b, tmpb, g2, b2, aid, out);
}